// Round 5
// baseline (9963.647 us; speedup 1.0000x reference)
//
#include <hip/hip_runtime.h>
#include <math.h>

#define NB    256
#define HDIM  512
#define LDIM  32
#define ADIM  200
#define NOUTV 8
#define NSTEP 256
#define NTHR  512
#define NWG   256
#define SCST  21

typedef __attribute__((ext_vector_type(8))) short sh8;
typedef __attribute__((ext_vector_type(4))) float f4;
union FU { uint4 u; sh8 s; };

__device__ __forceinline__ float b2f(unsigned int low16) { return __uint_as_float(low16 << 16); }

__global__ void __launch_bounds__(NTHR, 1)
sym_kernel(const int* __restrict__ instr,      // (8,256)
           const int* __restrict__ trueact,    // (33,256)
           const float* __restrict__ isv,      // (200,)
           const float* __restrict__ prim_emb, // (16,200)
           const float* __restrict__ gate_w,   // (1,128)
           const float* __restrict__ gate_b,   // (1,)
           const float* __restrict__ w_hh,     // (1536,512)
           const float* __restrict__ b_ih,     // (1536,)
           const float* __restrict__ b_hh,     // (1536,)
           const float* __restrict__ out_w,    // (8,200)
           const float* __restrict__ out_b,    // (8,)
           float* __restrict__ outp,           // 65536 + 8192
           unsigned int* __restrict__ ctrs,
           unsigned int* __restrict__ hbuf)    // 2 * 256 * 512 packed u32 (hi16|lo16)
{
  const int tid  = threadIdx.x;
  const int wgid = blockIdx.x;
  // XCD-local groups: members of a group share wgid%8
  const int x    = wgid & 7, q = wgid >> 3;
  const int gidx = x | ((q & 1) << 3);   // group 0..15
  const int jc   = q >> 1;               // member 0..15 (j-chunk; owns batch myb for attention)
  const int myb  = (gidx << 4) | jc;
  const int lane = tid & 63, wv = tid >> 6;
  const int mySet = jc >> 3, myRow = jc & 7;

  __shared__ __align__(16) unsigned short sHi[8 * 512];   // staged set h hi-plane, XOR-swizzled
  __shared__ __align__(16) unsigned short sLo[8 * 512];   // lo-plane (exact-h consumers only)
  __shared__ float sC[96 * SCST];                         // GEMM pre-acts r/z/n
  __shared__ __align__(16) float sPE[16 * ADIM];          // primitive_emb cache
  __shared__ __align__(16) float sAR[LDIM];
  __shared__ __align__(16) float sAW[LDIM];
  __shared__ float sGate;
  __shared__ __align__(16) float sSVe[LDIM * ADIM];       // epilogue only

  unsigned int* ctrS[2] = { ctrs + (gidx << 6), ctrs + (gidx << 6) + 32 };  // 128B apart

  // ---- per-thread loop invariants ----
  unsigned int wordpack = 0;
  #pragma unroll
  for (int wi = 0; wi < 8; ++wi)
    wordpack |= ((unsigned)instr[wi * NB + myb] & 15u) << (4 * wi);

  const int jj_t = (jc << 5) | (tid & 31);
  const float bi0 = b_ih[jj_t], bi1 = b_ih[512 + jj_t], bi2 = b_ih[1024 + jj_t];
  const float bh0 = b_hh[jj_t], bh1 = b_hh[512 + jj_t], bh2 = b_hh[1024 + jj_t];

  for (int i = tid; i < 16 * ADIM; i += NTHR) sPE[i] = prim_emb[i];

  // sv state in registers of threads 0..199 (own batch's scratch columns)
  float sv[LDIM];
  {
    const float v = (tid < ADIM) ? isv[tid] : 0.f;
    #pragma unroll
    for (int l = 0; l < LDIM; ++l) sv[l] = v;
  }
  {
    unsigned int* h0 = hbuf + (size_t)myb * HDIM;
    for (int k = tid; k < HDIM; k += NTHR) h0[k] = (k & 1) ? 0x3F800000u : 0u;  // bf16(1.0)|0
  }

  // ---- shared register file: weights (wv<6) / SK column (wv6) / gate_w (wv7) ----
  unsigned int reg[128];
  if (wv < 6) {
    const int n = lane & 15, quad = lane >> 4;
    const int row96 = (wv << 4) | n;
    const int g = row96 >> 5;
    const int jj = (jc << 5) | (row96 & 31);
    const float* wrow = w_hh + (size_t)(g * 512 + jj) * 512;
    #pragma unroll
    for (int kk = 0; kk < 16; ++kk) {
      const float4 w0 = *(const float4*)(wrow + kk * 32 + quad * 8);
      const float4 w1 = *(const float4*)(wrow + kk * 32 + quad * 8 + 4);
      float e[8] = {w0.x, w0.y, w0.z, w0.w, w1.x, w1.y, w1.z, w1.w};
      unsigned int hi16[8], lo16[8];
      #pragma unroll
      for (int t = 0; t < 8; ++t) {
        const unsigned int b = __float_as_uint(e[t]);
        hi16[t] = b >> 16;
        const float rest = e[t] - __uint_as_float(b & 0xFFFF0000u);
        lo16[t] = __float_as_uint(rest) >> 16;
      }
      #pragma unroll
      for (int p = 0; p < 4; ++p) {
        reg[kk * 4 + p]      = hi16[2 * p] | (hi16[2 * p + 1] << 16);
        reg[64 + kk * 4 + p] = lo16[2 * p] | (lo16[2 * p + 1] << 16);
      }
    }
  } else if (wv == 6) {
    const int l = lane & 31;
    #pragma unroll 1
    for (int k = 0; k < 128; ++k) {
      const float div = expf((float)(k & ~1) * (-9.210340371976184f / 128.0f));
      const float ang = (float)l * div;
      reg[k] = __float_as_uint((k & 1) ? cosf(ang) : sinf(ang));
    }
  } else {
    reg[0] = __float_as_uint(gate_w[2 * lane]);
    reg[1] = __float_as_uint(gate_w[2 * lane + 1]);
  }

  __syncthreads();   // h0 stores drained (vmcnt0), sPE ready
  if (tid == 0) {
    __hip_atomic_fetch_add(ctrS[0], 1u, __ATOMIC_ACQ_REL, __HIP_MEMORY_SCOPE_AGENT);
    __hip_atomic_fetch_add(ctrS[1], 1u, __ATOMIC_ACQ_REL, __HIP_MEMORY_SCOPE_AGENT);
  }

  const float gbias = gate_b[0];

  for (int step = 0; step < NSTEP; ++step) {
    const unsigned int* hc = hbuf + (size_t)(step & 1) * (NB * HDIM);
    unsigned int*       hn = hbuf + (size_t)((step & 1) ^ 1) * (NB * HDIM);
    const unsigned int target = 16u * (unsigned)(step + 1);

    #pragma unroll 1
    for (int set = 0; set < 2; ++set) {
      unsigned int* ctr = ctrS[set];
      const bool own = (mySet == set);

      // ---- wait: other set's phase has been covering this settle window ----
      if (tid == 0) {
        while (__hip_atomic_load(ctr, __ATOMIC_ACQUIRE, __HIP_MEMORY_SCOPE_AGENT) < target) {
          __builtin_amdgcn_s_sleep(1);
        }
      }
      __syncthreads();

      // ---- stage 8 rows (set's batches), packed u32 -> swizzled hi/lo planes ----
      {
        const uint4* src = (const uint4*)(hc + (size_t)((gidx << 4) + set * 8) * HDIM);
        #pragma unroll
        for (int it = 0; it < 2; ++it) {
          const int idx  = tid + it * NTHR;        // 0..1023
          const int row  = idx >> 7;
          const int colb = (idx & 127) << 3;       // byte offset in plane row
          const uint4 xx = src[idx];
          const int off = row * 1024 + (colb ^ (row << 4));
          *(uint2*)((char*)sHi + off) = make_uint2(
            (xx.x >> 16) | (xx.y & 0xFFFF0000u),
            (xx.z >> 16) | (xx.w & 0xFFFF0000u));
          *(uint2*)((char*)sLo + off) = make_uint2(
            (xx.x & 0xFFFFu) | (xx.y << 16),
            (xx.z & 0xFFFFu) | (xx.w << 16));
        }
      }
      __syncthreads();

      // ---- region 1: MFMA (waves 0-5) || attn (wave 6, own set) || gate (wave 7, own set) ----
      if (wv < 6) {
        const int n = lane & 15, quad = lane >> 4;
        const int arow = n & 7;                    // rows 8-15 duplicate 0-7 (results discarded)
        f4 a0 = {0.f, 0.f, 0.f, 0.f}, a1 = a0;
        #pragma unroll
        for (int kk = 0; kk < 16; ++kk) {
          const int off = arow * 1024 + (((kk << 6) | (quad << 4)) ^ (arow << 4));
          FU fah, fbh, fbl;
          fah.u = *(const uint4*)((const char*)sHi + off);
          fbh.u = make_uint4(reg[kk * 4], reg[kk * 4 + 1], reg[kk * 4 + 2], reg[kk * 4 + 3]);
          fbl.u = make_uint4(reg[64 + kk * 4], reg[64 + kk * 4 + 1], reg[64 + kk * 4 + 2], reg[64 + kk * 4 + 3]);
          a0 = __builtin_amdgcn_mfma_f32_16x16x32_bf16(fah.s, fbh.s, a0, 0, 0, 0);
          a1 = __builtin_amdgcn_mfma_f32_16x16x32_bf16(fah.s, fbl.s, a1, 0, 0, 0);
        }
        const int row96 = (wv << 4) | n;
        #pragma unroll
        for (int i = 0; i < 4; ++i)
          sC[row96 * SCST + (quad << 2) + i] = a0[i] + a1[i];
      } else if (wv == 6) {
        if (own) {
          const int l = lane & 31, sel = lane >> 5;
          const int swz = myRow << 4;
          float ac0 = 0.f, ac1 = 0.f, ac2 = 0.f, ac3 = 0.f;
          #pragma unroll
          for (int c = 0; c < 16; ++c) {
            const int byte0 = (128 + sel * 128 + c * 8) * 2;
            const int off = myRow * 1024 + (byte0 ^ swz);
            const uint4 hb = *(const uint4*)((const char*)sHi + off);
            const uint4 lb = *(const uint4*)((const char*)sLo + off);
            ac0 = fmaf(b2f(hb.x & 0xFFFFu) + b2f(lb.x & 0xFFFFu), __uint_as_float(reg[c * 8 + 0]), ac0);
            ac1 = fmaf(__uint_as_float(hb.x & 0xFFFF0000u) + __uint_as_float(lb.x & 0xFFFF0000u),
                       __uint_as_float(reg[c * 8 + 1]), ac1);
            ac2 = fmaf(b2f(hb.y & 0xFFFFu) + b2f(lb.y & 0xFFFFu), __uint_as_float(reg[c * 8 + 2]), ac2);
            ac3 = fmaf(__uint_as_float(hb.y & 0xFFFF0000u) + __uint_as_float(lb.y & 0xFFFF0000u),
                       __uint_as_float(reg[c * 8 + 3]), ac3);
            ac0 = fmaf(b2f(hb.z & 0xFFFFu) + b2f(lb.z & 0xFFFFu), __uint_as_float(reg[c * 8 + 4]), ac0);
            ac1 = fmaf(__uint_as_float(hb.z & 0xFFFF0000u) + __uint_as_float(lb.z & 0xFFFF0000u),
                       __uint_as_float(reg[c * 8 + 5]), ac1);
            ac2 = fmaf(b2f(hb.w & 0xFFFFu) + b2f(lb.w & 0xFFFFu), __uint_as_float(reg[c * 8 + 6]), ac2);
            ac3 = fmaf(__uint_as_float(hb.w & 0xFFFF0000u) + __uint_as_float(lb.w & 0xFFFF0000u),
                       __uint_as_float(reg[c * 8 + 7]), ac3);
          }
          float acc = (ac0 + ac1) + (ac2 + ac3);
          float mx = acc;
          #pragma unroll
          for (int m = 1; m < 32; m <<= 1) mx = fmaxf(mx, __shfl_xor(mx, m, 32));
          const float ev = __expf(acc - mx);
          float s = ev;
          #pragma unroll
          for (int m = 1; m < 32; m <<= 1) s += __shfl_xor(s, m, 32);
          (sel ? sAW : sAR)[l] = ev / s;
        }
      } else if (own) {   // wv == 7: gate
        const int swz = myRow << 4;
        const int off = myRow * 1024 + ((768 + 4 * lane) ^ swz);
        const unsigned int hb = *(const unsigned int*)((const char*)sHi + off);
        const unsigned int lb = *(const unsigned int*)((const char*)sLo + off);
        const float e0 = b2f(hb & 0xFFFFu) + b2f(lb & 0xFFFFu);
        const float e1 = __uint_as_float(hb & 0xFFFF0000u) + __uint_as_float(lb & 0xFFFF0000u);
        float part = fmaf(e0, __uint_as_float(reg[0]), e1 * __uint_as_float(reg[1]));
        #pragma unroll
        for (int m = 1; m < 64; m <<= 1) part += __shfl_xor(part, m, 64);
        if (lane == 0) sGate = 1.0f / (1.0f + __expf(-(part + gbias)));
      }
      __syncthreads();

      // ---- region 2: GRU combine + RNE-packed h store (tid<256) ; sv update (own, tid<200) ----
      if (tid < 256) {
        const int b = tid >> 5;                    // batch row 0..7 in set
        const int jcol = tid & 31;
        const float accR = sC[jcol * SCST + b];
        const float accZ = sC[(32 + jcol) * SCST + b];
        const float accN = sC[(64 + jcol) * SCST + b];
        const float r  = 1.f / (1.f + __expf(-(accR + bh0 + bi0)));
        const float z  = 1.f / (1.f + __expf(-(accZ + bh1 + bi1)));
        const float nn = tanhf(fmaf(r, accN + bh2, bi2));
        const int hoff = b * 1024 + ((jj_t * 2) ^ (b << 4));
        const float hold = b2f(*(const unsigned short*)((const char*)sHi + hoff))
                         + b2f(*(const unsigned short*)((const char*)sLo + hoff));
        const float hnew = fmaf(z, hold - nn, nn);
        const unsigned int u  = __float_as_uint(hnew);
        const unsigned int rb = (u + 0x7FFFu + ((u >> 16) & 1u)) & 0xFFFF0000u;  // RNE hi
        const float rest = hnew - __uint_as_float(rb);
        const unsigned int lob = __float_as_uint(rest) >> 16;
        hn[(size_t)((gidx << 4) + set * 8 + b) * HDIM + jj_t] = rb | lob;
      }
      if (own && tid < ADIM) {
        const int word = (wordpack >> ((step >> 5) << 2)) & 15u;
        const float g = sGate;
        const float pv = sPE[word * ADIM + tid];
        float rv = 0.f;
        const f4* ar4 = (const f4*)sAR;
        #pragma unroll
        for (int j = 0; j < 8; ++j) {
          const f4 a = ar4[j];
          rv = fmaf(a.x, sv[4 * j],     rv);
          rv = fmaf(a.y, sv[4 * j + 1], rv);
          rv = fmaf(a.z, sv[4 * j + 2], rv);
          rv = fmaf(a.w, sv[4 * j + 3], rv);
        }
        const float nv = fmaf(g, pv, (1.f - g) * rv);
        const f4* aw4 = (const f4*)sAW;
        #pragma unroll
        for (int j = 0; j < 8; ++j) {
          const f4 w = aw4[j];
          sv[4 * j]     = fmaf(w.x, nv - sv[4 * j],     sv[4 * j]);
          sv[4 * j + 1] = fmaf(w.y, nv - sv[4 * j + 1], sv[4 * j + 1]);
          sv[4 * j + 2] = fmaf(w.z, nv - sv[4 * j + 2], sv[4 * j + 2]);
          sv[4 * j + 3] = fmaf(w.w, nv - sv[4 * j + 3], sv[4 * j + 3]);
        }
      }
      __syncthreads();   // h stores drained before signal

      if (tid == 0)
        __hip_atomic_fetch_add(ctr, 1u, __ATOMIC_ACQ_REL, __HIP_MEMORY_SCOPE_AGENT);
    }
  }

  // ---- epilogue: dump sv, then actions = log_softmax(sv @ out_w.T + out_b), (b,v,l) ----
  if (tid < ADIM) {
    #pragma unroll
    for (int l = 0; l < LDIM; ++l) sSVe[l * ADIM + tid] = sv[l];
  }
  __syncthreads();

  if (tid < 256) {
    const int l = tid >> 3, v = tid & 7;
    const float* svrow = sSVe + l * ADIM;
    const float* wrow  = out_w + v * ADIM;
    float acc = out_b[v];
    #pragma unroll 8
    for (int a = 0; a < ADIM; ++a) acc = fmaf(svrow[a], wrow[a], acc);
    float mx = acc;
    #pragma unroll
    for (int m = 1; m < 8; m <<= 1) mx = fmaxf(mx, __shfl_xor(mx, m, 8));
    const float e = __expf(acc - mx);
    float s = e;
    #pragma unroll
    for (int m = 1; m < 8; m <<= 1) s += __shfl_xor(s, m, 8);
    outp[(size_t)myb * (NOUTV * LDIM) + v * LDIM + l] = acc - mx - logf(s);
  }
  if (tid < LDIM) {
    outp[NB * NOUTV * LDIM + myb * LDIM + tid] = (float)trueact[(tid + 1) * NB + myb];
  }
}

extern "C" void kernel_launch(void* const* d_in, const int* in_sizes, int n_in,
                              void* d_out, int out_size, void* d_ws, size_t ws_size,
                              hipStream_t stream) {
  const int*   instr   = (const int*)d_in[0];
  const int*   trueact = (const int*)d_in[1];
  const float* isv     = (const float*)d_in[2];
  // d_in[3] = program_emb (unused by reference math)
  const float* prim    = (const float*)d_in[4];
  const float* gate_w  = (const float*)d_in[5];
  const float* gate_b  = (const float*)d_in[6];
  // d_in[7] = w_ih (multiplied by zeros; only b_ih matters)
  const float* w_hh    = (const float*)d_in[8];
  const float* b_ih    = (const float*)d_in[9];
  const float* b_hh    = (const float*)d_in[10];
  const float* out_w   = (const float*)d_in[11];
  const float* out_b   = (const float*)d_in[12];
  float* outp = (float*)d_out;

  unsigned int* ctrs = (unsigned int*)d_ws;                  // 16 groups * 2 sets * 128B
  unsigned int* hbuf = (unsigned int*)((char*)d_ws + 4096);  // 2 * 256 * 512 u32 = 1 MB

  hipMemsetAsync(d_ws, 0, 4096, stream);

  void* args[] = { (void*)&instr, (void*)&trueact, (void*)&isv, (void*)&prim,
                   (void*)&gate_w, (void*)&gate_b, (void*)&w_hh, (void*)&b_ih,
                   (void*)&b_hh, (void*)&out_w, (void*)&out_b, (void*)&outp,
                   (void*)&ctrs, (void*)&hbuf };
  hipLaunchCooperativeKernel((const void*)sym_kernel, dim3(NWG), dim3(NTHR),
                             args, 0, stream);
}

// Round 6
// 6122.364 us; speedup vs baseline: 1.6274x; 1.6274x over previous
//
#include <hip/hip_runtime.h>
#include <math.h>

#define NB    256
#define HDIM  512
#define LDIM  32
#define ADIM  200
#define NOUTV 8
#define NSTEP 256
#define NTHR  512
#define NWG   256
#define SCST  21
#define ROWB  1040   // hi-tile row stride in bytes: 1040 % 128 = 16 -> bank-slot shift per row

typedef __attribute__((ext_vector_type(8))) short sh8;
typedef __attribute__((ext_vector_type(4))) float f4;
union FU { uint4 u; sh8 s; };

__device__ __forceinline__ float bhi(unsigned int w) { return __uint_as_float(w & 0xFFFF0000u); }
__device__ __forceinline__ float blo(unsigned int w) { return __uint_as_float(w << 16); }
__device__ __forceinline__ float pk2f(unsigned int w) { return bhi(w) + blo(w); }

__global__ void __launch_bounds__(NTHR, 1)
sym_kernel(const int* __restrict__ instr,      // (8,256)
           const int* __restrict__ trueact,    // (33,256)
           const float* __restrict__ isv,      // (200,)
           const float* __restrict__ prim_emb, // (16,200)
           const float* __restrict__ gate_w,   // (1,128)
           const float* __restrict__ gate_b,   // (1,)
           const float* __restrict__ w_hh,     // (1536,512)
           const float* __restrict__ b_ih,     // (1536,)
           const float* __restrict__ b_hh,     // (1536,)
           const float* __restrict__ out_w,    // (8,200)
           const float* __restrict__ out_b,    // (8,)
           float* __restrict__ outp,           // 65536 + 8192
           unsigned int* __restrict__ ctrs,
           unsigned int* __restrict__ hbuf)    // 2 * 256 * 512 packed u32 (hi16|lo16)
{
  const int tid  = threadIdx.x;
  const int wgid = blockIdx.x;
  // XCD-local groups: members of a group share wgid%8 (round-robin XCD dispatch)
  const int gidx = (wgid & 7) | (((wgid >> 3) & 1) << 3);   // group 0..15
  const int jc   = wgid >> 4;                               // member 0..15
  const int myb  = (gidx << 4) | jc;
  const int lane = tid & 63, wv = tid >> 6;

  __shared__ __align__(16) unsigned char sHiB[16 * ROWB];  // h hi-plane tile, stride-1040 rows
  __shared__ float sC[96 * SCST];                          // GEMM pre-acts r/z/n
  __shared__ __align__(16) float sPE[16 * ADIM];           // primitive_emb cache
  __shared__ __align__(16) float sAR[LDIM];
  __shared__ __align__(16) float sAW[LDIM];
  __shared__ float sGate;
  __shared__ __align__(16) float sSVe[LDIM * ADIM];        // epilogue only

  unsigned int* ctr = ctrs + (gidx << 5);   // one 128B line per group

  // ---- per-thread loop invariants ----
  unsigned int wordpack = 0;
  #pragma unroll
  for (int wi = 0; wi < 8; ++wi)
    wordpack |= ((unsigned)instr[wi * NB + myb] & 15u) << (4 * wi);

  const int jj_t = (jc << 5) | (tid & 31);
  const float bi0 = b_ih[jj_t], bi1 = b_ih[512 + jj_t], bi2 = b_ih[1024 + jj_t];
  const float bh0 = b_hh[jj_t], bh1 = b_hh[512 + jj_t], bh2 = b_hh[1024 + jj_t];

  for (int i = tid; i < 16 * ADIM; i += NTHR) sPE[i] = prim_emb[i];

  // sv state in registers of threads 0..199
  float sv[LDIM];
  {
    const float v = (tid < ADIM) ? isv[tid] : 0.f;
    #pragma unroll
    for (int l = 0; l < LDIM; ++l) sv[l] = v;
  }
  {
    unsigned int* h0 = hbuf + (size_t)myb * HDIM;
    for (int k = tid; k < HDIM; k += NTHR) h0[k] = (k & 1) ? 0x3F800000u : 0u;  // bf16(1.0)|0
  }

  // ---- shared register file: weights (wv<6) / SK column (wv6) / gate_w (wv7) ----
  unsigned int reg[128];
  if (wv < 6) {
    const int n = lane & 15, quad = lane >> 4;
    const int row96 = (wv << 4) | n;
    const int g = row96 >> 5;
    const int jj = (jc << 5) | (row96 & 31);
    const float* wrow = w_hh + (size_t)(g * 512 + jj) * 512;
    #pragma unroll
    for (int kk = 0; kk < 16; ++kk) {
      const float4 w0 = *(const float4*)(wrow + kk * 32 + quad * 8);
      const float4 w1 = *(const float4*)(wrow + kk * 32 + quad * 8 + 4);
      float e[8] = {w0.x, w0.y, w0.z, w0.w, w1.x, w1.y, w1.z, w1.w};
      unsigned int hi16[8], lo16[8];
      #pragma unroll
      for (int t = 0; t < 8; ++t) {
        const unsigned int b = __float_as_uint(e[t]);
        hi16[t] = b >> 16;
        const float rest = e[t] - __uint_as_float(b & 0xFFFF0000u);
        lo16[t] = __float_as_uint(rest) >> 16;
      }
      #pragma unroll
      for (int p = 0; p < 4; ++p) {
        reg[kk * 4 + p]      = hi16[2 * p] | (hi16[2 * p + 1] << 16);
        reg[64 + kk * 4 + p] = lo16[2 * p] | (lo16[2 * p + 1] << 16);
      }
    }
  } else if (wv == 6) {
    const int l = lane & 31;
    #pragma unroll 1
    for (int k = 0; k < 128; ++k) {
      const float div = expf((float)(k & ~1) * (-9.210340371976184f / 128.0f));
      const float ang = (float)l * div;
      reg[k] = __float_as_uint((k & 1) ? cosf(ang) : sinf(ang));
    }
  } else {
    reg[0] = __float_as_uint(gate_w[2 * lane]);
    reg[1] = __float_as_uint(gate_w[2 * lane + 1]);
  }

  // ---- initial barrier ----
  __syncthreads();   // h0 stores drained per-wave before barrier
  if (tid == 448)
    __hip_atomic_fetch_add(ctr, 1u, __ATOMIC_RELEASE, __HIP_MEMORY_SCOPE_AGENT);
  if (tid == 448) {
    while (__hip_atomic_load(ctr, __ATOMIC_ACQUIRE, __HIP_MEMORY_SCOPE_AGENT) < 16u) {
      __builtin_amdgcn_s_sleep(1);
    }
  }
  __syncthreads();

  const float gbias = gate_b[0];

  for (int step = 0; step < NSTEP; ++step) {
    const unsigned int* hc = hbuf + (size_t)(step & 1) * (NB * HDIM);
    unsigned int*       hn = hbuf + (size_t)((step & 1) ^ 1) * (NB * HDIM);

    // ---- early global loads (L2-hot, latency hides under staging) ----
    const unsigned int hold_u = hc[(size_t)((gidx << 4) | (tid >> 5)) * HDIM + jj_t];
    uint2 gate2;
    if (wv == 7) gate2 = *(const uint2*)(hc + (size_t)myb * HDIM + 384 + 2 * lane);

    // ---- stage hi-plane only: packed u32 -> bf16-hi tile, stride-1040 rows ----
    {
      const uint4* src = (const uint4*)(hc + (size_t)(gidx << 4) * HDIM);
      #pragma unroll
      for (int it = 0; it < 4; ++it) {
        const int idx  = tid + it * NTHR;        // 0..2047
        const int row  = idx >> 7;
        const int col4 = idx & 127;              // 4-elem chunk within row
        const uint4 xx = src[idx];
        *(uint2*)(sHiB + row * ROWB + col4 * 8) = make_uint2(
          (xx.x >> 16) | (xx.y & 0xFFFF0000u),
          (xx.z >> 16) | (xx.w & 0xFFFF0000u));
      }
    }
    __syncthreads();

    // ---- region 1: MFMA (waves 0-5) || attention (wave 6) || gate (wave 7) ----
    if (wv < 6) {
      const int n = lane & 15, quad = lane >> 4;
      const unsigned char* arow = sHiB + n * ROWB + quad * 16;
      f4 a0 = {0.f, 0.f, 0.f, 0.f}, a1 = a0;
      #pragma unroll
      for (int kk = 0; kk < 16; ++kk) {
        FU fah, fbh, fbl;
        fah.u = *(const uint4*)(arow + (kk << 6));
        fbh.u = make_uint4(reg[kk * 4], reg[kk * 4 + 1], reg[kk * 4 + 2], reg[kk * 4 + 3]);
        fbl.u = make_uint4(reg[64 + kk * 4], reg[64 + kk * 4 + 1], reg[64 + kk * 4 + 2], reg[64 + kk * 4 + 3]);
        a0 = __builtin_amdgcn_mfma_f32_16x16x32_bf16(fah.s, fbh.s, a0, 0, 0, 0);
        a1 = __builtin_amdgcn_mfma_f32_16x16x32_bf16(fah.s, fbl.s, a1, 0, 0, 0);
      }
      const int row96 = (wv << 4) | n;
      #pragma unroll
      for (int i = 0; i < 4; ++i)
        sC[row96 * SCST + (quad << 2) + i] = a0[i] + a1[i];
    } else if (wv == 6) {
      const int l = lane & 31, sel = lane >> 5;
      const uint4* prow = (const uint4*)(hc + (size_t)myb * HDIM + 128 + sel * 128);
      float ac0 = 0.f, ac1 = 0.f, ac2 = 0.f, ac3 = 0.f;
      #pragma unroll 1
      for (int cc = 0; cc < 4; ++cc) {         // 4 chunks of 8 uint4 (VGPR cap)
        uint4 qb[8];
        #pragma unroll
        for (int i = 0; i < 8; ++i) qb[i] = prow[cc * 8 + i];
        #pragma unroll
        for (int i = 0; i < 8; ++i) {
          const int k = cc * 32 + i * 4;
          ac0 = fmaf(pk2f(qb[i].x), __uint_as_float(reg[k]),     ac0);
          ac1 = fmaf(pk2f(qb[i].y), __uint_as_float(reg[k + 1]), ac1);
          ac2 = fmaf(pk2f(qb[i].z), __uint_as_float(reg[k + 2]), ac2);
          ac3 = fmaf(pk2f(qb[i].w), __uint_as_float(reg[k + 3]), ac3);
        }
      }
      float acc = (ac0 + ac1) + (ac2 + ac3);
      float mx = acc;
      #pragma unroll
      for (int m = 1; m < 32; m <<= 1) mx = fmaxf(mx, __shfl_xor(mx, m, 32));
      const float ev = __expf(acc - mx);
      float s = ev;
      #pragma unroll
      for (int m = 1; m < 32; m <<= 1) s += __shfl_xor(s, m, 32);
      (sel ? sAW : sAR)[l] = ev / s;
    } else {   // wave 7: gate
      float part = fmaf(pk2f(gate2.x), __uint_as_float(reg[0]),
                        pk2f(gate2.y) * __uint_as_float(reg[1]));
      #pragma unroll
      for (int m = 1; m < 64; m <<= 1) part += __shfl_xor(part, m, 64);
      if (lane == 0) sGate = 1.0f / (1.0f + __expf(-(part + gbias)));
    }
    __syncthreads();

    // ---- region 2: GRU combine + RNE-packed h store (all 512 threads) ----
    {
      const int b = tid >> 5, jcol = tid & 31;
      const float accR = sC[jcol * SCST + b];
      const float accZ = sC[(32 + jcol) * SCST + b];
      const float accN = sC[(64 + jcol) * SCST + b];
      const float r  = 1.f / (1.f + __expf(-(accR + bh0 + bi0)));
      const float z  = 1.f / (1.f + __expf(-(accZ + bh1 + bi1)));
      const float nn = tanhf(fmaf(r, accN + bh2, bi2));
      const float hold = pk2f(hold_u);
      const float hnew = fmaf(z, hold - nn, nn);
      const unsigned int u  = __float_as_uint(hnew);
      const unsigned int rb = (u + 0x7FFFu + ((u >> 16) & 1u)) & 0xFFFF0000u;  // RNE hi
      const float rest = hnew - __uint_as_float(rb);
      const unsigned int lob = __float_as_uint(rest) >> 16;
      hn[(size_t)((gidx << 4) | b) * HDIM + jj_t] = rb | lob;
    }
    __syncthreads();   // all h stores drained (per-wave vmcnt0 before barrier)

    // ---- signal, then sv-update overlaps the settle; wave 7 polls ----
    if (tid == 448)
      __hip_atomic_fetch_add(ctr, 1u, __ATOMIC_RELEASE, __HIP_MEMORY_SCOPE_AGENT);

    if (tid < ADIM) {
      const int word = (wordpack >> ((step >> 5) << 2)) & 15u;
      const float g = sGate;
      const float pv = sPE[word * ADIM + tid];
      float rv = 0.f;
      const f4* ar4 = (const f4*)sAR;
      #pragma unroll
      for (int j = 0; j < 8; ++j) {
        const f4 a = ar4[j];
        rv = fmaf(a.x, sv[4 * j],     rv);
        rv = fmaf(a.y, sv[4 * j + 1], rv);
        rv = fmaf(a.z, sv[4 * j + 2], rv);
        rv = fmaf(a.w, sv[4 * j + 3], rv);
      }
      const float nv = fmaf(g, pv, (1.f - g) * rv);
      const f4* aw4 = (const f4*)sAW;
      #pragma unroll
      for (int j = 0; j < 8; ++j) {
        const f4 w = aw4[j];
        sv[4 * j]     = fmaf(w.x, nv - sv[4 * j],     sv[4 * j]);
        sv[4 * j + 1] = fmaf(w.y, nv - sv[4 * j + 1], sv[4 * j + 1]);
        sv[4 * j + 2] = fmaf(w.z, nv - sv[4 * j + 2], sv[4 * j + 2]);
        sv[4 * j + 3] = fmaf(w.w, nv - sv[4 * j + 3], sv[4 * j + 3]);
      }
    } else if (tid == 448) {
      const unsigned int target = 16u * (unsigned)(step + 2);
      while (__hip_atomic_load(ctr, __ATOMIC_ACQUIRE, __HIP_MEMORY_SCOPE_AGENT) < target) {
        __builtin_amdgcn_s_sleep(1);
      }
    }
    __syncthreads();
  }

  // ---- epilogue: dump sv, then actions = log_softmax(sv @ out_w.T + out_b), (b,v,l) ----
  if (tid < ADIM) {
    #pragma unroll
    for (int l = 0; l < LDIM; ++l) sSVe[l * ADIM + tid] = sv[l];
  }
  __syncthreads();

  if (tid < 256) {
    const int l = tid >> 3, v = tid & 7;
    const float* svrow = sSVe + l * ADIM;
    const float* wrow  = out_w + v * ADIM;
    float acc = out_b[v];
    #pragma unroll 8
    for (int a = 0; a < ADIM; ++a) acc = fmaf(svrow[a], wrow[a], acc);
    float mx = acc;
    #pragma unroll
    for (int m = 1; m < 8; m <<= 1) mx = fmaxf(mx, __shfl_xor(mx, m, 8));
    const float e = __expf(acc - mx);
    float s = e;
    #pragma unroll
    for (int m = 1; m < 8; m <<= 1) s += __shfl_xor(s, m, 8);
    outp[(size_t)myb * (NOUTV * LDIM) + v * LDIM + l] = acc - mx - logf(s);
  }
  if (tid < LDIM) {
    outp[NB * NOUTV * LDIM + myb * LDIM + tid] = (float)trueact[(tid + 1) * NB + myb];
  }
}

extern "C" void kernel_launch(void* const* d_in, const int* in_sizes, int n_in,
                              void* d_out, int out_size, void* d_ws, size_t ws_size,
                              hipStream_t stream) {
  const int*   instr   = (const int*)d_in[0];
  const int*   trueact = (const int*)d_in[1];
  const float* isv     = (const float*)d_in[2];
  // d_in[3] = program_emb (unused by reference math)
  const float* prim    = (const float*)d_in[4];
  const float* gate_w  = (const float*)d_in[5];
  const float* gate_b  = (const float*)d_in[6];
  // d_in[7] = w_ih (multiplied by zeros; only b_ih matters)
  const float* w_hh    = (const float*)d_in[8];
  const float* b_ih    = (const float*)d_in[9];
  const float* b_hh    = (const float*)d_in[10];
  const float* out_w   = (const float*)d_in[11];
  const float* out_b   = (const float*)d_in[12];
  float* outp = (float*)d_out;

  unsigned int* ctrs = (unsigned int*)d_ws;                  // 16 groups * 128B
  unsigned int* hbuf = (unsigned int*)((char*)d_ws + 4096);  // 2 * 256 * 512 u32 = 1 MB

  hipMemsetAsync(d_ws, 0, 4096, stream);

  void* args[] = { (void*)&instr, (void*)&trueact, (void*)&isv, (void*)&prim,
                   (void*)&gate_w, (void*)&gate_b, (void*)&w_hh, (void*)&b_ih,
                   (void*)&b_hh, (void*)&out_w, (void*)&out_b, (void*)&outp,
                   (void*)&ctrs, (void*)&hbuf };
  hipLaunchCooperativeKernel((const void*)sym_kernel, dim3(NWG), dim3(NTHR),
                             args, 0, stream);
}

// Round 7
// 4225.665 us; speedup vs baseline: 2.3579x; 1.4489x over previous
//
#include <hip/hip_runtime.h>
#include <math.h>

#define NB    256
#define HDIM  512
#define LDIM  32
#define ADIM  200
#define NOUTV 8
#define NSTEP 256
#define NTHR  512
#define NWG   256
#define SCST  21

typedef __attribute__((ext_vector_type(8))) short sh8;
typedef __attribute__((ext_vector_type(4))) float f4;
union FU { uint4 u; sh8 s; };

__device__ __forceinline__ float b2f(unsigned int low16) { return __uint_as_float(low16 << 16); }

__global__ void __launch_bounds__(NTHR, 1)
sym_kernel(const int* __restrict__ instr,      // (8,256)
           const int* __restrict__ trueact,    // (33,256)
           const float* __restrict__ isv,      // (200,)
           const float* __restrict__ prim_emb, // (16,200)
           const float* __restrict__ gate_w,   // (1,128)
           const float* __restrict__ gate_b,   // (1,)
           const float* __restrict__ w_hh,     // (1536,512)
           const float* __restrict__ b_ih,     // (1536,)
           const float* __restrict__ b_hh,     // (1536,)
           const float* __restrict__ out_w,    // (8,200)
           const float* __restrict__ out_b,    // (8,)
           float* __restrict__ outp,           // 65536 + 8192
           unsigned int* __restrict__ ctrs,
           unsigned int* __restrict__ hbuf)    // 2 * 256 * 512 packed u32 (hi16|lo16)
{
  const int tid  = threadIdx.x;
  const int wgid = blockIdx.x;
  // XCD-local groups: members of a group share wgid%8 (round-robin XCD dispatch)
  const int x    = wgid & 7, q = wgid >> 3;
  const int gidx = x | ((q & 1) << 3);   // group 0..15
  const int jc   = q >> 1;               // member 0..15 (j-chunk; owns batch myb)
  const int myb  = (gidx << 4) | jc;
  const int lane = tid & 63, wv = tid >> 6;

  __shared__ __align__(16) unsigned short sHi[16 * 512];   // h hi-plane, XOR-swizzled
  __shared__ __align__(16) unsigned short sLo[16 * 512];   // lo-plane (only row jc written)
  __shared__ float sC[96 * SCST];                          // GEMM pre-acts r/z/n
  __shared__ float sSKt[128 * 32];                         // SK^T (prologue only)
  __shared__ __align__(16) float sPE[16 * ADIM];           // primitive_emb cache
  __shared__ __align__(16) float sAR[LDIM];
  __shared__ __align__(16) float sAW[LDIM];
  __shared__ float sGate;
  __shared__ __align__(16) float sSVe[LDIM * ADIM];        // epilogue only

  unsigned int* ctr = ctrs + (gidx << 5);   // one 128B line per group

  // ---- per-thread loop invariants ----
  unsigned int wordpack = 0;
  #pragma unroll
  for (int wi = 0; wi < 8; ++wi)
    wordpack |= ((unsigned)instr[wi * NB + myb] & 15u) << (4 * wi);

  const int jj_t = (jc << 5) | (tid & 31);
  const float bi0 = b_ih[jj_t], bi1 = b_ih[512 + jj_t], bi2 = b_ih[1024 + jj_t];
  const float bh0 = b_hh[jj_t], bh1 = b_hh[512 + jj_t], bh2 = b_hh[1024 + jj_t];

  // ---- prologue fills ----
  for (int i = tid; i < 128 * 32; i += NTHR) {
    const int k = i >> 5, l = i & 31;
    const float div = expf((float)(k & ~1) * (-9.210340371976184f / 128.0f));
    const float ang = (float)l * div;
    sSKt[i] = (k & 1) ? cosf(ang) : sinf(ang);
  }
  for (int i = tid; i < 16 * ADIM; i += NTHR) sPE[i] = prim_emb[i];

  // sv state in registers of threads 0..199; h_old carried per thread (b=tid>>5, col jj_t)
  float sv[LDIM];
  {
    const float v = (tid < ADIM) ? isv[tid] : 0.f;
    #pragma unroll
    for (int l = 0; l < LDIM; ++l) sv[l] = v;
  }
  float hold_reg = (jj_t & 1) ? 1.0f : 0.0f;   // pe[0] tiled

  {
    unsigned int* h0 = hbuf + (size_t)myb * HDIM;
    for (int k = tid; k < HDIM; k += NTHR) h0[k] = (k & 1) ? 0x3F800000u : 0u;  // bf16(1.0)|0
  }
  __syncthreads();   // sSKt ready

  // ---- shared register file: weights (wv<6) / SK column (wv6) / gate_w (wv7) ----
  // All reg[] accesses MUST be compile-time static (rule #20: dynamic idx -> scratch).
  unsigned int reg[128];
  if (wv < 6) {
    const int n = lane & 15, quad = lane >> 4;
    const int row96 = (wv << 4) | n;
    const int g = row96 >> 5;
    const int jj = (jc << 5) | (row96 & 31);
    const float* wrow = w_hh + (size_t)(g * 512 + jj) * 512;
    #pragma unroll
    for (int kk = 0; kk < 16; ++kk) {
      const float4 w0 = *(const float4*)(wrow + kk * 32 + quad * 8);
      const float4 w1 = *(const float4*)(wrow + kk * 32 + quad * 8 + 4);
      float e[8] = {w0.x, w0.y, w0.z, w0.w, w1.x, w1.y, w1.z, w1.w};
      unsigned int hi16[8], lo16[8];
      #pragma unroll
      for (int t = 0; t < 8; ++t) {
        const unsigned int b = __float_as_uint(e[t]);
        hi16[t] = b >> 16;
        const float rest = e[t] - __uint_as_float(b & 0xFFFF0000u);
        lo16[t] = __float_as_uint(rest) >> 16;
      }
      #pragma unroll
      for (int p = 0; p < 4; ++p) {
        reg[kk * 4 + p]      = hi16[2 * p] | (hi16[2 * p + 1] << 16);
        reg[64 + kk * 4 + p] = lo16[2 * p] | (lo16[2 * p + 1] << 16);
      }
    }
  } else if (wv == 6) {
    const int l = lane & 31;
    #pragma unroll
    for (int k = 0; k < 128; ++k) reg[k] = __float_as_uint(sSKt[k * 32 + l]);   // static idx
  } else {
    reg[0] = __float_as_uint(gate_w[2 * lane]);
    reg[1] = __float_as_uint(gate_w[2 * lane + 1]);
  }

  // ---- initial barrier (round-3 proven mechanism) ----
  __syncthreads();   // h0 stores drained
  if (tid == 448) {
    __hip_atomic_fetch_add(ctr, 1u, __ATOMIC_RELEASE, __HIP_MEMORY_SCOPE_AGENT);
    while (__hip_atomic_load(ctr, __ATOMIC_ACQUIRE, __HIP_MEMORY_SCOPE_AGENT) < 16u) {
      __builtin_amdgcn_s_sleep(1);
    }
  }
  __syncthreads();

  const float gbias = gate_b[0];

  for (int step = 0; step < NSTEP; ++step) {
    const unsigned int* hc = hbuf + (size_t)(step & 1) * (NB * HDIM);
    unsigned int*       hn = hbuf + (size_t)((step & 1) ^ 1) * (NB * HDIM);

    // ---- stage: hi-plane all rows, lo-plane only row jc (wave-uniform predicate) ----
    {
      const uint4* src = (const uint4*)(hc + (size_t)(gidx << 4) * HDIM);
      #pragma unroll
      for (int it = 0; it < 2; ++it) {
        const int c   = tid + it * NTHR;          // 0..1023
        const int row = c >> 6;
        const int kb  = (c & 63) << 4;            // byte offset within 1024B plane row
        const uint4 x0 = src[c * 2], x1 = src[c * 2 + 1];
        const int off = row * 1024 + (kb ^ ((row & 7) << 4));
        *(uint4*)((char*)sHi + off) = make_uint4(
          (x0.x >> 16) | (x0.y & 0xFFFF0000u),
          (x0.z >> 16) | (x0.w & 0xFFFF0000u),
          (x1.x >> 16) | (x1.y & 0xFFFF0000u),
          (x1.z >> 16) | (x1.w & 0xFFFF0000u));
        if (row == jc)
          *(uint4*)((char*)sLo + off) = make_uint4(
            (x0.x & 0xFFFFu) | (x0.y << 16),
            (x0.z & 0xFFFFu) | (x0.w << 16),
            (x1.x & 0xFFFFu) | (x1.y << 16),
            (x1.z & 0xFFFFu) | (x1.w << 16));
      }
    }
    __syncthreads();

    // ---- region 1: MFMA (waves 0-5, hi-only A) || attn (wave 6) || gate (wave 7) ----
    if (wv < 6) {
      const int n = lane & 15, quad = lane >> 4;
      const int sw = (n & 7) << 4;
      f4 a0 = {0.f, 0.f, 0.f, 0.f}, a1 = a0;
      #pragma unroll
      for (int kk = 0; kk < 16; ++kk) {
        const int off = n * 1024 + (((kk << 6) | (quad << 4)) ^ sw);
        FU fah, fbh, fbl;
        fah.u = *(const uint4*)((const char*)sHi + off);
        fbh.u = make_uint4(reg[kk * 4], reg[kk * 4 + 1], reg[kk * 4 + 2], reg[kk * 4 + 3]);
        fbl.u = make_uint4(reg[64 + kk * 4], reg[64 + kk * 4 + 1], reg[64 + kk * 4 + 2], reg[64 + kk * 4 + 3]);
        a0 = __builtin_amdgcn_mfma_f32_16x16x32_bf16(fah.s, fbh.s, a0, 0, 0, 0);
        a1 = __builtin_amdgcn_mfma_f32_16x16x32_bf16(fah.s, fbl.s, a1, 0, 0, 0);
      }
      const int row96 = (wv << 4) | n;
      #pragma unroll
      for (int i = 0; i < 4; ++i)
        sC[row96 * SCST + (quad << 2) + i] = a0[i] + a1[i];
    } else if (wv == 6) {
      const int l = lane & 31, sel = lane >> 5;
      const int sw = (jc & 7) << 4;
      float ac0 = 0.f, ac1 = 0.f, ac2 = 0.f, ac3 = 0.f;
      #pragma unroll
      for (int c = 0; c < 32; ++c) {
        const int kbyte = (128 + sel * 128 + c * 4) * 2;
        const int off = jc * 1024 + (kbyte ^ sw);
        const uint2 hb = *(const uint2*)((const char*)sHi + off);
        const uint2 lb = *(const uint2*)((const char*)sLo + off);
        ac0 = fmaf(b2f(hb.x & 0xFFFFu) + b2f(lb.x & 0xFFFFu), __uint_as_float(reg[c * 4]), ac0);
        ac1 = fmaf(__uint_as_float(hb.x & 0xFFFF0000u) + __uint_as_float(lb.x & 0xFFFF0000u),
                   __uint_as_float(reg[c * 4 + 1]), ac1);
        ac2 = fmaf(b2f(hb.y & 0xFFFFu) + b2f(lb.y & 0xFFFFu), __uint_as_float(reg[c * 4 + 2]), ac2);
        ac3 = fmaf(__uint_as_float(hb.y & 0xFFFF0000u) + __uint_as_float(lb.y & 0xFFFF0000u),
                   __uint_as_float(reg[c * 4 + 3]), ac3);
      }
      float acc = (ac0 + ac1) + (ac2 + ac3);
      float mx = acc;
      #pragma unroll
      for (int m = 1; m < 32; m <<= 1) mx = fmaxf(mx, __shfl_xor(mx, m, 32));
      const float ev = __expf(acc - mx);
      float s = ev;
      #pragma unroll
      for (int m = 1; m < 32; m <<= 1) s += __shfl_xor(s, m, 32);
      (sel ? sAW : sAR)[l] = ev / s;
    } else {   // wave 7: gate
      const int sw = (jc & 7) << 4;
      const int off = jc * 1024 + ((768 + 4 * lane) ^ sw);
      const unsigned int hb = *(const unsigned int*)((const char*)sHi + off);
      const unsigned int lb = *(const unsigned int*)((const char*)sLo + off);
      const float e0 = b2f(hb & 0xFFFFu) + b2f(lb & 0xFFFFu);
      const float e1 = __uint_as_float(hb & 0xFFFF0000u) + __uint_as_float(lb & 0xFFFF0000u);
      float part = fmaf(e0, __uint_as_float(reg[0]), e1 * __uint_as_float(reg[1]));
      #pragma unroll
      for (int m = 1; m < 64; m <<= 1) part += __shfl_xor(part, m, 64);
      if (lane == 0) sGate = 1.0f / (1.0f + __expf(-(part + gbias)));
    }
    __syncthreads();

    // ---- region 2: GRU combine + packed h store (hold carried in register) ----
    {
      const int b = tid >> 5, jcol = tid & 31;
      const float accR = sC[jcol * SCST + b];
      const float accZ = sC[(32 + jcol) * SCST + b];
      const float accN = sC[(64 + jcol) * SCST + b];
      const float r  = 1.f / (1.f + __expf(-(accR + bh0 + bi0)));
      const float z  = 1.f / (1.f + __expf(-(accZ + bh1 + bi1)));
      const float nn = tanhf(fmaf(r, accN + bh2, bi2));
      const float hnew = fmaf(z, hold_reg - nn, nn);
      hold_reg = hnew;
      const unsigned int u  = __float_as_uint(hnew);
      const unsigned int rb = (u + 0x7FFFu + ((u >> 16) & 1u)) & 0xFFFF0000u;  // RNE hi
      const float rest = hnew - __uint_as_float(rb);
      const unsigned int lob = __float_as_uint(rest) >> 16;
      hn[(size_t)((gidx << 4) | b) * HDIM + jj_t] = rb | lob;
    }
    __syncthreads();   // h stores drained before signal

    // ---- signal early; sv update (registers) overlaps the settle; one poller ----
    if (tid == 448)
      __hip_atomic_fetch_add(ctr, 1u, __ATOMIC_RELEASE, __HIP_MEMORY_SCOPE_AGENT);

    if (tid < ADIM) {
      const int word = (wordpack >> ((step >> 5) << 2)) & 15u;
      const float g = sGate;
      const float pv = sPE[word * ADIM + tid];
      float rv = 0.f;
      const f4* ar4 = (const f4*)sAR;
      #pragma unroll
      for (int j = 0; j < 8; ++j) {
        const f4 a = ar4[j];
        rv = fmaf(a.x, sv[4 * j],     rv);
        rv = fmaf(a.y, sv[4 * j + 1], rv);
        rv = fmaf(a.z, sv[4 * j + 2], rv);
        rv = fmaf(a.w, sv[4 * j + 3], rv);
      }
      const float nv = fmaf(g, pv, (1.f - g) * rv);
      const f4* aw4 = (const f4*)sAW;
      #pragma unroll
      for (int j = 0; j < 8; ++j) {
        const f4 w = aw4[j];
        sv[4 * j]     = fmaf(w.x, nv - sv[4 * j],     sv[4 * j]);
        sv[4 * j + 1] = fmaf(w.y, nv - sv[4 * j + 1], sv[4 * j + 1]);
        sv[4 * j + 2] = fmaf(w.z, nv - sv[4 * j + 2], sv[4 * j + 2]);
        sv[4 * j + 3] = fmaf(w.w, nv - sv[4 * j + 3], sv[4 * j + 3]);
      }
    } else if (tid == 448) {
      const unsigned int target = 16u * (unsigned)(step + 2);
      while (__hip_atomic_load(ctr, __ATOMIC_ACQUIRE, __HIP_MEMORY_SCOPE_AGENT) < target) {
        __builtin_amdgcn_s_sleep(1);
      }
    }
    __syncthreads();
  }

  // ---- epilogue: dump sv, then actions = log_softmax(sv @ out_w.T + out_b), (b,v,l) ----
  if (tid < ADIM) {
    #pragma unroll
    for (int l = 0; l < LDIM; ++l) sSVe[l * ADIM + tid] = sv[l];
  }
  __syncthreads();

  if (tid < 256) {
    const int l = tid >> 3, v = tid & 7;
    const float* svrow = sSVe + l * ADIM;
    const float* wrow  = out_w + v * ADIM;
    float acc = out_b[v];
    #pragma unroll 8
    for (int a = 0; a < ADIM; ++a) acc = fmaf(svrow[a], wrow[a], acc);
    float mx = acc;
    #pragma unroll
    for (int m = 1; m < 8; m <<= 1) mx = fmaxf(mx, __shfl_xor(mx, m, 8));
    const float e = __expf(acc - mx);
    float s = e;
    #pragma unroll
    for (int m = 1; m < 8; m <<= 1) s += __shfl_xor(s, m, 8);
    outp[(size_t)myb * (NOUTV * LDIM) + v * LDIM + l] = acc - mx - logf(s);
  }
  if (tid < LDIM) {
    outp[NB * NOUTV * LDIM + myb * LDIM + tid] = (float)trueact[(tid + 1) * NB + myb];
  }
}

extern "C" void kernel_launch(void* const* d_in, const int* in_sizes, int n_in,
                              void* d_out, int out_size, void* d_ws, size_t ws_size,
                              hipStream_t stream) {
  const int*   instr   = (const int*)d_in[0];
  const int*   trueact = (const int*)d_in[1];
  const float* isv     = (const float*)d_in[2];
  // d_in[3] = program_emb (unused by reference math)
  const float* prim    = (const float*)d_in[4];
  const float* gate_w  = (const float*)d_in[5];
  const float* gate_b  = (const float*)d_in[6];
  // d_in[7] = w_ih (multiplied by zeros; only b_ih matters)
  const float* w_hh    = (const float*)d_in[8];
  const float* b_ih    = (const float*)d_in[9];
  const float* b_hh    = (const float*)d_in[10];
  const float* out_w   = (const float*)d_in[11];
  const float* out_b   = (const float*)d_in[12];
  float* outp = (float*)d_out;

  unsigned int* ctrs = (unsigned int*)d_ws;                  // 16 groups * 128B
  unsigned int* hbuf = (unsigned int*)((char*)d_ws + 4096);  // 2 * 256 * 512 u32 = 1 MB

  hipMemsetAsync(d_ws, 0, 4096, stream);

  void* args[] = { (void*)&instr, (void*)&trueact, (void*)&isv, (void*)&prim,
                   (void*)&gate_w, (void*)&gate_b, (void*)&w_hh, (void*)&b_ih,
                   (void*)&b_hh, (void*)&out_w, (void*)&out_b, (void*)&outp,
                   (void*)&ctrs, (void*)&hbuf };
  hipLaunchCooperativeKernel((const void*)sym_kernel, dim3(NWG), dim3(NTHR),
                             args, 0, stream);
}

// Round 8
// 3775.769 us; speedup vs baseline: 2.6388x; 1.1192x over previous
//
#include <hip/hip_runtime.h>
#include <math.h>

#define NB    256
#define HDIM  512
#define LDIM  32
#define ADIM  200
#define NOUTV 8
#define NSTEP 256
#define NTHR  512
#define NWG   256
#define SCST  21

typedef __attribute__((ext_vector_type(8))) short sh8;
typedef __attribute__((ext_vector_type(4))) float f4;
union FU { uint4 u; sh8 s; };

__device__ __forceinline__ float b2f(unsigned int low16) { return __uint_as_float(low16 << 16); }

__global__ void __launch_bounds__(NTHR, 1)
sym_kernel(const int* __restrict__ instr,      // (8,256)
           const int* __restrict__ trueact,    // (33,256)
           const float* __restrict__ isv,      // (200,)
           const float* __restrict__ prim_emb, // (16,200)
           const float* __restrict__ gate_w,   // (1,128)
           const float* __restrict__ gate_b,   // (1,)
           const float* __restrict__ w_hh,     // (1536,512)
           const float* __restrict__ b_ih,     // (1536,)
           const float* __restrict__ b_hh,     // (1536,)
           const float* __restrict__ out_w,    // (8,200)
           const float* __restrict__ out_b,    // (8,)
           float* __restrict__ outp,           // 65536 + 8192
           unsigned int* __restrict__ ctrs,
           unsigned int* __restrict__ hbuf)    // 2 * 256 * 512 packed u32 (hi16|lo16)
{
  const int tid  = threadIdx.x;
  const int wgid = blockIdx.x;
  // XCD-local groups: members of a group share wgid%8 (round-robin XCD dispatch)
  const int x    = wgid & 7, q = wgid >> 3;
  const int gidx = x | ((q & 1) << 3);   // group 0..15
  const int jc   = q >> 1;               // member 0..15 (j-chunk; owns batch myb)
  const int myb  = (gidx << 4) | jc;
  const int lane = tid & 63, wv = tid >> 6;

  __shared__ __align__(16) unsigned short sHi[16 * 512];   // h hi-plane, XOR-swizzled
  __shared__ __align__(16) unsigned short sLo[16 * 512];   // lo-plane (only row jc written)
  __shared__ float sC[96 * SCST];                          // GEMM pre-acts r/z/n
  __shared__ float sSKt[128 * 32];                         // SK^T (prologue only)
  __shared__ __align__(16) float sPE[16 * ADIM];           // primitive_emb cache
  __shared__ __align__(16) float sAR[LDIM];
  __shared__ __align__(16) float sAW[LDIM];
  __shared__ float sGate;
  __shared__ __align__(16) float sSVe[LDIM * ADIM];        // epilogue only

  unsigned int* ctr = ctrs + (gidx << 5);   // one 128B line per group

  // ---- per-thread loop invariants ----
  unsigned int wordpack = 0;
  #pragma unroll
  for (int wi = 0; wi < 8; ++wi)
    wordpack |= ((unsigned)instr[wi * NB + myb] & 15u) << (4 * wi);

  const int jj_t = (jc << 5) | (tid & 31);
  const float bi0 = b_ih[jj_t], bi1 = b_ih[512 + jj_t], bi2 = b_ih[1024 + jj_t];
  const float bh0 = b_hh[jj_t], bh1 = b_hh[512 + jj_t], bh2 = b_hh[1024 + jj_t];

  // ---- prologue fills ----
  for (int i = tid; i < 128 * 32; i += NTHR) {
    const int k = i >> 5, l = i & 31;
    const float div = expf((float)(k & ~1) * (-9.210340371976184f / 128.0f));
    const float ang = (float)l * div;
    sSKt[i] = (k & 1) ? cosf(ang) : sinf(ang);
  }
  for (int i = tid; i < 16 * ADIM; i += NTHR) sPE[i] = prim_emb[i];

  // sv state in registers of threads 0..199; h_old carried per thread (b=tid>>5, col jj_t)
  float sv[LDIM];
  {
    const float v = (tid < ADIM) ? isv[tid] : 0.f;
    #pragma unroll
    for (int l = 0; l < LDIM; ++l) sv[l] = v;
  }
  float hold_reg = (jj_t & 1) ? 1.0f : 0.0f;   // pe[0] tiled

  {
    unsigned int* h0 = hbuf + (size_t)myb * HDIM;
    for (int k = tid; k < HDIM; k += NTHR) h0[k] = (k & 1) ? 0x3F800000u : 0u;  // bf16(1.0)|0
  }
  __syncthreads();   // sSKt ready

  // ---- shared register file: weights (wv<6) / SK column (wv6) / gate_w (wv7) ----
  // All reg[] accesses MUST be compile-time static (rule #20: dynamic idx -> scratch).
  unsigned int reg[128];
  if (wv < 6) {
    const int n = lane & 15, quad = lane >> 4;
    const int row96 = (wv << 4) | n;
    const int g = row96 >> 5;
    const int jj = (jc << 5) | (row96 & 31);
    const float* wrow = w_hh + (size_t)(g * 512 + jj) * 512;
    #pragma unroll
    for (int kk = 0; kk < 16; ++kk) {
      const float4 w0 = *(const float4*)(wrow + kk * 32 + quad * 8);
      const float4 w1 = *(const float4*)(wrow + kk * 32 + quad * 8 + 4);
      float e[8] = {w0.x, w0.y, w0.z, w0.w, w1.x, w1.y, w1.z, w1.w};
      unsigned int hi16[8], lo16[8];
      #pragma unroll
      for (int t = 0; t < 8; ++t) {
        const unsigned int b = __float_as_uint(e[t]);
        hi16[t] = b >> 16;
        const float rest = e[t] - __uint_as_float(b & 0xFFFF0000u);
        lo16[t] = __float_as_uint(rest) >> 16;
      }
      #pragma unroll
      for (int p = 0; p < 4; ++p) {
        reg[kk * 4 + p]      = hi16[2 * p] | (hi16[2 * p + 1] << 16);
        reg[64 + kk * 4 + p] = lo16[2 * p] | (lo16[2 * p + 1] << 16);
      }
    }
  } else if (wv == 6) {
    const int l = lane & 31;
    #pragma unroll
    for (int k = 0; k < 128; ++k) reg[k] = __float_as_uint(sSKt[k * 32 + l]);   // static idx
  } else {
    reg[0] = __float_as_uint(gate_w[2 * lane]);
    reg[1] = __float_as_uint(gate_w[2 * lane + 1]);
  }

  // ---- initial barrier (round-3 proven: signal+poll back-to-back, one thread) ----
  __syncthreads();   // h0 stores drained
  if (tid == 448) {
    __hip_atomic_fetch_add(ctr, 1u, __ATOMIC_RELEASE, __HIP_MEMORY_SCOPE_AGENT);
    while (__hip_atomic_load(ctr, __ATOMIC_ACQUIRE, __HIP_MEMORY_SCOPE_AGENT) < 16u) {
      __builtin_amdgcn_s_sleep(1);
    }
  }
  __syncthreads();

  const float gbias = gate_b[0];

  for (int step = 0; step < NSTEP; ++step) {
    const unsigned int* hc = hbuf + (size_t)(step & 1) * (NB * HDIM);
    unsigned int*       hn = hbuf + (size_t)((step & 1) ^ 1) * (NB * HDIM);

    // ---- stage: hi-plane all rows, lo-plane only row jc (wave-uniform predicate) ----
    {
      const uint4* src = (const uint4*)(hc + (size_t)(gidx << 4) * HDIM);
      #pragma unroll
      for (int it = 0; it < 2; ++it) {
        const int c   = tid + it * NTHR;          // 0..1023
        const int row = c >> 6;
        const int kb  = (c & 63) << 4;            // byte offset within 1024B plane row
        const uint4 x0 = src[c * 2], x1 = src[c * 2 + 1];
        const int off = row * 1024 + (kb ^ ((row & 7) << 4));
        *(uint4*)((char*)sHi + off) = make_uint4(
          (x0.x >> 16) | (x0.y & 0xFFFF0000u),
          (x0.z >> 16) | (x0.w & 0xFFFF0000u),
          (x1.x >> 16) | (x1.y & 0xFFFF0000u),
          (x1.z >> 16) | (x1.w & 0xFFFF0000u));
        if (row == jc)
          *(uint4*)((char*)sLo + off) = make_uint4(
            (x0.x & 0xFFFFu) | (x0.y << 16),
            (x0.z & 0xFFFFu) | (x0.w << 16),
            (x1.x & 0xFFFFu) | (x1.y << 16),
            (x1.z & 0xFFFFu) | (x1.w << 16));
      }
    }
    __syncthreads();

    // ---- region 1: MFMA (waves 0-5, hi-only A) || attn (wave 6) || gate (wave 7) ----
    if (wv < 6) {
      const int n = lane & 15, quad = lane >> 4;
      const int sw = (n & 7) << 4;
      f4 a0 = {0.f, 0.f, 0.f, 0.f}, a1 = a0;
      #pragma unroll
      for (int kk = 0; kk < 16; ++kk) {
        const int off = n * 1024 + (((kk << 6) | (quad << 4)) ^ sw);
        FU fah, fbh, fbl;
        fah.u = *(const uint4*)((const char*)sHi + off);
        fbh.u = make_uint4(reg[kk * 4], reg[kk * 4 + 1], reg[kk * 4 + 2], reg[kk * 4 + 3]);
        fbl.u = make_uint4(reg[64 + kk * 4], reg[64 + kk * 4 + 1], reg[64 + kk * 4 + 2], reg[64 + kk * 4 + 3]);
        a0 = __builtin_amdgcn_mfma_f32_16x16x32_bf16(fah.s, fbh.s, a0, 0, 0, 0);
        a1 = __builtin_amdgcn_mfma_f32_16x16x32_bf16(fah.s, fbl.s, a1, 0, 0, 0);
      }
      const int row96 = (wv << 4) | n;
      #pragma unroll
      for (int i = 0; i < 4; ++i)
        sC[row96 * SCST + (quad << 2) + i] = a0[i] + a1[i];
    } else if (wv == 6) {
      const int l = lane & 31, sel = lane >> 5;
      const int sw = (jc & 7) << 4;
      float ac0 = 0.f, ac1 = 0.f, ac2 = 0.f, ac3 = 0.f;
      #pragma unroll
      for (int c = 0; c < 32; ++c) {
        const int kbyte = (128 + sel * 128 + c * 4) * 2;
        const int off = jc * 1024 + (kbyte ^ sw);
        const uint2 hb = *(const uint2*)((const char*)sHi + off);
        const uint2 lb = *(const uint2*)((const char*)sLo + off);
        ac0 = fmaf(b2f(hb.x & 0xFFFFu) + b2f(lb.x & 0xFFFFu), __uint_as_float(reg[c * 4]), ac0);
        ac1 = fmaf(__uint_as_float(hb.x & 0xFFFF0000u) + __uint_as_float(lb.x & 0xFFFF0000u),
                   __uint_as_float(reg[c * 4 + 1]), ac1);
        ac2 = fmaf(b2f(hb.y & 0xFFFFu) + b2f(lb.y & 0xFFFFu), __uint_as_float(reg[c * 4 + 2]), ac2);
        ac3 = fmaf(__uint_as_float(hb.y & 0xFFFF0000u) + __uint_as_float(lb.y & 0xFFFF0000u),
                   __uint_as_float(reg[c * 4 + 3]), ac3);
      }
      float acc = (ac0 + ac1) + (ac2 + ac3);
      float mx = acc;
      #pragma unroll
      for (int m = 1; m < 32; m <<= 1) mx = fmaxf(mx, __shfl_xor(mx, m, 32));
      const float ev = __expf(acc - mx);
      float s = ev;
      #pragma unroll
      for (int m = 1; m < 32; m <<= 1) s += __shfl_xor(s, m, 32);
      (sel ? sAW : sAR)[l] = ev / s;
    } else {   // wave 7: gate
      const int sw = (jc & 7) << 4;
      const int off = jc * 1024 + ((768 + 4 * lane) ^ sw);
      const unsigned int hb = *(const unsigned int*)((const char*)sHi + off);
      const unsigned int lb = *(const unsigned int*)((const char*)sLo + off);
      const float e0 = b2f(hb & 0xFFFFu) + b2f(lb & 0xFFFFu);
      const float e1 = __uint_as_float(hb & 0xFFFF0000u) + __uint_as_float(lb & 0xFFFF0000u);
      float part = fmaf(e0, __uint_as_float(reg[0]), e1 * __uint_as_float(reg[1]));
      #pragma unroll
      for (int m = 1; m < 64; m <<= 1) part += __shfl_xor(part, m, 64);
      if (lane == 0) sGate = 1.0f / (1.0f + __expf(-(part + gbias)));
    }
    __syncthreads();

    // ---- region 2: GRU combine + packed h store; then sv update (tid<200, registers) ----
    {
      const int b = tid >> 5, jcol = tid & 31;
      const float accR = sC[jcol * SCST + b];
      const float accZ = sC[(32 + jcol) * SCST + b];
      const float accN = sC[(64 + jcol) * SCST + b];
      const float r  = 1.f / (1.f + __expf(-(accR + bh0 + bi0)));
      const float z  = 1.f / (1.f + __expf(-(accZ + bh1 + bi1)));
      const float nn = tanhf(fmaf(r, accN + bh2, bi2));
      const float hnew = fmaf(z, hold_reg - nn, nn);
      hold_reg = hnew;
      const unsigned int u  = __float_as_uint(hnew);
      const unsigned int rb = (u + 0x7FFFu + ((u >> 16) & 1u)) & 0xFFFF0000u;  // RNE hi
      const float rest = hnew - __uint_as_float(rb);
      const unsigned int lob = __float_as_uint(rest) >> 16;
      hn[(size_t)((gidx << 4) | b) * HDIM + jj_t] = rb | lob;
    }
    if (tid < ADIM) {
      const int word = (wordpack >> ((step >> 5) << 2)) & 15u;
      const float g = sGate;
      const float pv = sPE[word * ADIM + tid];
      float rv = 0.f;
      const f4* ar4 = (const f4*)sAR;
      #pragma unroll
      for (int j = 0; j < 8; ++j) {
        const f4 a = ar4[j];
        rv = fmaf(a.x, sv[4 * j],     rv);
        rv = fmaf(a.y, sv[4 * j + 1], rv);
        rv = fmaf(a.z, sv[4 * j + 2], rv);
        rv = fmaf(a.w, sv[4 * j + 3], rv);
      }
      const float nv = fmaf(g, pv, (1.f - g) * rv);
      const f4* aw4 = (const f4*)sAW;
      #pragma unroll
      for (int j = 0; j < 8; ++j) {
        const f4 w = aw4[j];
        sv[4 * j]     = fmaf(w.x, nv - sv[4 * j],     sv[4 * j]);
        sv[4 * j + 1] = fmaf(w.y, nv - sv[4 * j + 1], sv[4 * j + 1]);
        sv[4 * j + 2] = fmaf(w.z, nv - sv[4 * j + 2], sv[4 * j + 2]);
        sv[4 * j + 3] = fmaf(w.w, nv - sv[4 * j + 3], sv[4 * j + 3]);
      }
    }
    __syncthreads();   // all work done, h stores drained

    // ---- group barrier: signal + poll back-to-back (minimal acquire iterations) ----
    if (tid == 448) {
      __hip_atomic_fetch_add(ctr, 1u, __ATOMIC_RELEASE, __HIP_MEMORY_SCOPE_AGENT);
      const unsigned int target = 16u * (unsigned)(step + 2);
      while (__hip_atomic_load(ctr, __ATOMIC_ACQUIRE, __HIP_MEMORY_SCOPE_AGENT) < target) {
        __builtin_amdgcn_s_sleep(1);
      }
    }
    __syncthreads();
  }

  // ---- epilogue: dump sv, then actions = log_softmax(sv @ out_w.T + out_b), (b,v,l) ----
  if (tid < ADIM) {
    #pragma unroll
    for (int l = 0; l < LDIM; ++l) sSVe[l * ADIM + tid] = sv[l];
  }
  __syncthreads();

  if (tid < 256) {
    const int l = tid >> 3, v = tid & 7;
    const float* svrow = sSVe + l * ADIM;
    const float* wrow  = out_w + v * ADIM;
    float acc = out_b[v];
    #pragma unroll 8
    for (int a = 0; a < ADIM; ++a) acc = fmaf(svrow[a], wrow[a], acc);
    float mx = acc;
    #pragma unroll
    for (int m = 1; m < 8; m <<= 1) mx = fmaxf(mx, __shfl_xor(mx, m, 8));
    const float e = __expf(acc - mx);
    float s = e;
    #pragma unroll
    for (int m = 1; m < 8; m <<= 1) s += __shfl_xor(s, m, 8);
    outp[(size_t)myb * (NOUTV * LDIM) + v * LDIM + l] = acc - mx - logf(s);
  }
  if (tid < LDIM) {
    outp[NB * NOUTV * LDIM + myb * LDIM + tid] = (float)trueact[(tid + 1) * NB + myb];
  }
}

extern "C" void kernel_launch(void* const* d_in, const int* in_sizes, int n_in,
                              void* d_out, int out_size, void* d_ws, size_t ws_size,
                              hipStream_t stream) {
  const int*   instr   = (const int*)d_in[0];
  const int*   trueact = (const int*)d_in[1];
  const float* isv     = (const float*)d_in[2];
  // d_in[3] = program_emb (unused by reference math)
  const float* prim    = (const float*)d_in[4];
  const float* gate_w  = (const float*)d_in[5];
  const float* gate_b  = (const float*)d_in[6];
  // d_in[7] = w_ih (multiplied by zeros; only b_ih matters)
  const float* w_hh    = (const float*)d_in[8];
  const float* b_ih    = (const float*)d_in[9];
  const float* b_hh    = (const float*)d_in[10];
  const float* out_w   = (const float*)d_in[11];
  const float* out_b   = (const float*)d_in[12];
  float* outp = (float*)d_out;

  unsigned int* ctrs = (unsigned int*)d_ws;                  // 16 groups * 128B
  unsigned int* hbuf = (unsigned int*)((char*)d_ws + 4096);  // 2 * 256 * 512 u32 = 1 MB

  hipMemsetAsync(d_ws, 0, 4096, stream);

  void* args[] = { (void*)&instr, (void*)&trueact, (void*)&isv, (void*)&prim,
                   (void*)&gate_w, (void*)&gate_b, (void*)&w_hh, (void*)&b_ih,
                   (void*)&b_hh, (void*)&out_w, (void*)&out_b, (void*)&outp,
                   (void*)&ctrs, (void*)&hbuf };
  hipLaunchCooperativeKernel((const void*)sym_kernel, dim3(NWG), dim3(NTHR),
                             args, 0, stream);
}

// Round 9
// 3430.424 us; speedup vs baseline: 2.9045x; 1.1007x over previous
//
#include <hip/hip_runtime.h>
#include <math.h>

#define NB    256
#define HDIM  512
#define LDIM  32
#define ADIM  200
#define NOUTV 8
#define NSTEP 256
#define NTHR  512
#define NWG   256
#define WPG   16
#define SCST  21

typedef __attribute__((ext_vector_type(8))) short sh8;
typedef __attribute__((ext_vector_type(4))) float f4;

union FU { uint4 u; sh8 s; };

__device__ __forceinline__ float b2f(unsigned int low16) { return __uint_as_float(low16 << 16); }

__device__ __forceinline__ void group_barrier(unsigned int* ctr, unsigned int target) {
  __syncthreads();
  if (threadIdx.x == 0) {
    __hip_atomic_fetch_add(ctr, 1u, __ATOMIC_RELEASE, __HIP_MEMORY_SCOPE_AGENT);
    while (__hip_atomic_load(ctr, __ATOMIC_ACQUIRE, __HIP_MEMORY_SCOPE_AGENT) < target) {
      __builtin_amdgcn_s_sleep(1);
    }
  }
  __syncthreads();
}

__global__ void __launch_bounds__(NTHR, 1)
sym_kernel(const int* __restrict__ instr,      // (8,256)
           const int* __restrict__ trueact,    // (33,256)
           const float* __restrict__ isv,      // (200,)
           const float* __restrict__ prim_emb, // (16,200)
           const float* __restrict__ gate_w,   // (1,128)
           const float* __restrict__ gate_b,   // (1,)
           const float* __restrict__ w_hh,     // (1536,512)
           const float* __restrict__ b_ih,     // (1536,)
           const float* __restrict__ b_hh,     // (1536,)
           const float* __restrict__ out_w,    // (8,200)
           const float* __restrict__ out_b,    // (8,)
           float* __restrict__ outp,           // 65536 + 8192
           unsigned int* __restrict__ ctrs,
           unsigned int* __restrict__ hbuf)    // 2 * 256 * 512 packed u32 (hi16|lo16)
{
  const int tid  = threadIdx.x;
  const int wgid = blockIdx.x;
  // XCD-local groups: members of a group share wgid%8
  const int x    = wgid & 7, q = wgid >> 3;
  const int gidx = x | ((q & 1) << 3);   // group 0..15
  const int jc   = q >> 1;               // member 0..15 (j-chunk; also my phase-A batch)
  const int myb  = (gidx << 4) | jc;
  const int lane = tid & 63, wv = tid >> 6;

  __shared__ __align__(16) unsigned short sHi[16 * 512];   // h hi-plane, XOR-swizzled
  __shared__ __align__(16) unsigned short sLo[16 * 512];   // h lo-plane
  __shared__ float sC[96 * SCST];                          // GEMM output r/z/n pre-acts
  __shared__ __align__(16) float sSV[LDIM * ADIM];         // my batch's scratch
  __shared__ __align__(16) float sNV[ADIM];
  __shared__ float sSKt[128 * 32];                         // SK^T [k][l] (prologue only)
  __shared__ __align__(16) float sPE[16 * ADIM];           // primitive_emb cache
  __shared__ float sAR[LDIM], sAW[LDIM];
  __shared__ float sGate;

  unsigned int* ctr = ctrs + (gidx << 5);   // one 128B cacheline per group

  // ---- per-thread loop invariants ----
  unsigned int wordpack = 0;
  #pragma unroll
  for (int wi = 0; wi < 8; ++wi)
    wordpack |= ((unsigned)instr[wi * NB + myb] & 15u) << (4 * wi);

  const int jj_t = (jc << 5) | (tid & 31);   // my combine j
  const float bi0 = b_ih[jj_t], bi1 = b_ih[512 + jj_t], bi2 = b_ih[1024 + jj_t];
  const float bh0 = b_hh[jj_t], bh1 = b_hh[512 + jj_t], bh2 = b_hh[1024 + jj_t];

  // ---- prologue fills ----
  for (int i = tid; i < 128 * 32; i += NTHR) {
    const int k = i >> 5, l = i & 31;
    const float div = expf((float)(k & ~1) * (-9.210340371976184f / 128.0f));
    const float ang = (float)l * div;
    sSKt[i] = (k & 1) ? cosf(ang) : sinf(ang);
  }
  for (int i = tid; i < 16 * ADIM; i += NTHR) sPE[i] = prim_emb[i];
  for (int i = tid; i < LDIM * ADIM; i += NTHR) sSV[i] = isv[i % ADIM];
  {
    unsigned int* h0 = hbuf + (size_t)myb * HDIM;
    for (int k = tid; k < HDIM; k += NTHR) h0[k] = (k & 1) ? 0x3F800000u : 0u;  // bf16(1.0)|0
  }
  __syncthreads();   // sSKt ready

  // ---- shared register file: weights (wv<6) / SK column (wv6) / gate_w (wv7) ----
  unsigned int reg[128];
  if (wv < 6) {
    const int n = lane & 15, quad = lane >> 4;
    const int row96 = (wv << 4) | n;
    const int g = row96 >> 5;
    const int jj = (jc << 5) | (row96 & 31);
    const float* wrow = w_hh + (size_t)(g * 512 + jj) * 512;
    #pragma unroll
    for (int kk = 0; kk < 16; ++kk) {
      const float4 w0 = *(const float4*)(wrow + kk * 32 + quad * 8);
      const float4 w1 = *(const float4*)(wrow + kk * 32 + quad * 8 + 4);
      float e[8] = {w0.x, w0.y, w0.z, w0.w, w1.x, w1.y, w1.z, w1.w};
      unsigned int hi16[8], lo16[8];
      #pragma unroll
      for (int t = 0; t < 8; ++t) {
        const unsigned int b = __float_as_uint(e[t]);
        hi16[t] = b >> 16;
        const float rest = e[t] - __uint_as_float(b & 0xFFFF0000u);
        lo16[t] = __float_as_uint(rest) >> 16;
      }
      #pragma unroll
      for (int p = 0; p < 4; ++p) {
        reg[kk * 4 + p]      = hi16[2 * p] | (hi16[2 * p + 1] << 16);
        reg[64 + kk * 4 + p] = lo16[2 * p] | (lo16[2 * p + 1] << 16);
      }
    }
  } else if (wv == 6) {
    const int l = lane & 31;
    #pragma unroll
    for (int k = 0; k < 128; ++k) reg[k] = __float_as_uint(sSKt[k * 32 + l]);
  } else {
    reg[0] = __float_as_uint(gate_w[2 * lane]);
    reg[1] = __float_as_uint(gate_w[2 * lane + 1]);
  }

  group_barrier(ctr, WPG);   // h0 of all group batches visible

  const float gbias = gate_b[0];
  unsigned int bar = 2;

  for (int step = 0; step < NSTEP; ++step, ++bar) {
    const unsigned int* hc = hbuf + (size_t)(step & 1) * (NB * HDIM);
    unsigned int*       hn = hbuf + (size_t)((step & 1) ^ 1) * (NB * HDIM);

    // ---- stage packed h -> swizzled hi/lo planes (1024 chunks of 8 elems) ----
    {
      const uint4* src = (const uint4*)(hc + (size_t)(gidx << 4) * HDIM);
      #pragma unroll
      for (int it = 0; it < 2; ++it) {
        const int c   = tid + it * NTHR;          // 0..1023
        const int row = c >> 6;
        const int kb  = (c & 63) << 4;
        const uint4 x0 = src[c * 2], x1 = src[c * 2 + 1];
        const int off = row * 1024 + (kb ^ ((row & 7) << 4));
        *(uint4*)((char*)sHi + off) = make_uint4(
          (x0.x >> 16) | (x0.y & 0xFFFF0000u),
          (x0.z >> 16) | (x0.w & 0xFFFF0000u),
          (x1.x >> 16) | (x1.y & 0xFFFF0000u),
          (x1.z >> 16) | (x1.w & 0xFFFF0000u));
        *(uint4*)((char*)sLo + off) = make_uint4(
          (x0.x & 0xFFFFu) | (x0.y << 16),
          (x0.z & 0xFFFFu) | (x0.w << 16),
          (x1.x & 0xFFFFu) | (x1.y << 16),
          (x1.z & 0xFFFFu) | (x1.w << 16));
      }
    }
    __syncthreads();

    // ---- region 1: MFMA hi-only (waves 0-5) || attention (wave 6) || gate (wave 7) ----
    if (wv < 6) {
      const int n = lane & 15, quad = lane >> 4;
      const int sw = (n & 7) << 4;
      f4 a0 = {0.f, 0.f, 0.f, 0.f}, a1 = a0;
      #pragma unroll
      for (int kk = 0; kk < 16; ++kk) {
        const int off = n * 1024 + (((kk << 6) | (quad << 4)) ^ sw);
        FU fah, fbh, fbl;
        fah.u = *(const uint4*)((const char*)sHi + off);
        fbh.u = make_uint4(reg[kk * 4], reg[kk * 4 + 1], reg[kk * 4 + 2], reg[kk * 4 + 3]);
        fbl.u = make_uint4(reg[64 + kk * 4], reg[64 + kk * 4 + 1], reg[64 + kk * 4 + 2], reg[64 + kk * 4 + 3]);
        a0 = __builtin_amdgcn_mfma_f32_16x16x32_bf16(fah.s, fbh.s, a0, 0, 0, 0);
        a1 = __builtin_amdgcn_mfma_f32_16x16x32_bf16(fah.s, fbl.s, a1, 0, 0, 0);
      }
      const int row96 = (wv << 4) | n;
      #pragma unroll
      for (int i = 0; i < 4; ++i)
        sC[row96 * SCST + (quad << 2) + i] = a0[i] + a1[i];
    } else if (wv == 6) {
      const int l = lane & 31, sel = lane >> 5;
      const int sw = (jc & 7) << 4;
      float ac0 = 0.f, ac1 = 0.f, ac2 = 0.f, ac3 = 0.f;
      #pragma unroll
      for (int c = 0; c < 32; ++c) {
        const int kbyte = (128 + sel * 128 + c * 4) * 2;
        const int off = jc * 1024 + (kbyte ^ sw);
        const uint2 hb = *(const uint2*)((const char*)sHi + off);
        const uint2 lb = *(const uint2*)((const char*)sLo + off);
        ac0 = fmaf(b2f(hb.x & 0xFFFFu) + b2f(lb.x & 0xFFFFu), __uint_as_float(reg[c * 4]), ac0);
        ac1 = fmaf(__uint_as_float(hb.x & 0xFFFF0000u) + __uint_as_float(lb.x & 0xFFFF0000u),
                   __uint_as_float(reg[c * 4 + 1]), ac1);
        ac2 = fmaf(b2f(hb.y & 0xFFFFu) + b2f(lb.y & 0xFFFFu), __uint_as_float(reg[c * 4 + 2]), ac2);
        ac3 = fmaf(__uint_as_float(hb.y & 0xFFFF0000u) + __uint_as_float(lb.y & 0xFFFF0000u),
                   __uint_as_float(reg[c * 4 + 3]), ac3);
      }
      float acc = (ac0 + ac1) + (ac2 + ac3);
      float mx = acc;
      #pragma unroll
      for (int m = 1; m < 32; m <<= 1) mx = fmaxf(mx, __shfl_xor(mx, m, 32));
      const float ev = __expf(acc - mx);
      float s = ev;
      #pragma unroll
      for (int m = 1; m < 32; m <<= 1) s += __shfl_xor(s, m, 32);
      (sel ? sAW : sAR)[l] = ev / s;
    } else {
      const int sw = (jc & 7) << 4;
      const int off = jc * 1024 + ((768 + 4 * lane) ^ sw);
      const unsigned int hb = *(const unsigned int*)((const char*)sHi + off);
      const unsigned int lb = *(const unsigned int*)((const char*)sLo + off);
      const float e0 = b2f(hb & 0xFFFFu) + b2f(lb & 0xFFFFu);
      const float e1 = __uint_as_float(hb & 0xFFFF0000u) + __uint_as_float(lb & 0xFFFF0000u);
      float part = fmaf(e0, __uint_as_float(reg[0]), e1 * __uint_as_float(reg[1]));
      #pragma unroll
      for (int m = 1; m < 64; m <<= 1) part += __shfl_xor(part, m, 64);
      if (lane == 0) sGate = 1.0f / (1.0f + __expf(-(part + gbias)));
    }
    __syncthreads();

    // ---- region 2: GRU combine + h store (all threads) ----
    {
      const int b = tid >> 5, jcol = tid & 31;
      const float accR = sC[jcol * SCST + b];
      const float accZ = sC[(32 + jcol) * SCST + b];
      const float accN = sC[(64 + jcol) * SCST + b];
      const float r  = 1.f / (1.f + __expf(-(accR + bh0 + bi0)));
      const float z  = 1.f / (1.f + __expf(-(accZ + bh1 + bi1)));
      const float nn = tanhf(fmaf(r, accN + bh2, bi2));
      const int hoff = b * 1024 + ((jj_t * 2) ^ ((b & 7) << 4));
      const float hold = b2f(*(const unsigned short*)((const char*)sHi + hoff))
                       + b2f(*(const unsigned short*)((const char*)sLo + hoff));
      const float hnew = fmaf(z, hold - nn, nn);
      const unsigned int hibits = __float_as_uint(hnew) & 0xFFFF0000u;
      const float rest = hnew - __uint_as_float(hibits);
      const unsigned int lobits = __float_as_uint(rest) >> 16;
      hn[(size_t)((gidx << 4) + b) * HDIM + jj_t] = hibits | lobits;
    }
    if (tid < ADIM) {
      const int word = (wordpack >> ((step >> 5) << 2)) & 15u;
      float rv = 0.f;
      #pragma unroll 8
      for (int l = 0; l < LDIM; ++l) rv = fmaf(sAR[l], sSV[l * ADIM + tid], rv);
      const float g = sGate;
      sNV[tid] = fmaf(g, sPE[word * ADIM + tid], (1.f - g) * rv);
    }
    __syncthreads();

    // ---- region 3: scratch update (vectorized) ----
    {
      const f4* nv4 = (const f4*)sNV;
      f4* sv4 = (f4*)sSV;
      #pragma unroll
      for (int it = 0; it < 4; ++it) {
        const int s4 = tid + it * NTHR;
        if (s4 < 1600) {
          const int l = s4 / 50, a4 = s4 - l * 50;
          const float w = sAW[l];
          const f4 nv = nv4[a4];
          f4 sv = sv4[s4];
          sv.x = fmaf(w, nv.x - sv.x, sv.x);
          sv.y = fmaf(w, nv.y - sv.y, sv.y);
          sv.z = fmaf(w, nv.z - sv.z, sv.z);
          sv.w = fmaf(w, nv.w - sv.w, sv.w);
          sv4[s4] = sv;
        }
      }
    }

    group_barrier(ctr, bar * WPG);
  }

  // ---- epilogue: actions = log_softmax(sv @ out_w.T + out_b), (b, v, l) ----
  if (tid < 256) {
    const int l = tid >> 3, v = tid & 7;
    const float* svrow = sSV + l * ADIM;
    const float* wrow  = out_w + v * ADIM;
    float acc = out_b[v];
    #pragma unroll 8
    for (int a = 0; a < ADIM; ++a) acc = fmaf(svrow[a], wrow[a], acc);
    float mx = acc;
    #pragma unroll
    for (int m = 1; m < 8; m <<= 1) mx = fmaxf(mx, __shfl_xor(mx, m, 8));
    const float e = __expf(acc - mx);
    float s = e;
    #pragma unroll
    for (int m = 1; m < 8; m <<= 1) s += __shfl_xor(s, m, 8);
    outp[(size_t)myb * (NOUTV * LDIM) + v * LDIM + l] = acc - mx - logf(s);
  }
  if (tid < LDIM) {
    outp[NB * NOUTV * LDIM + myb * LDIM + tid] = (float)trueact[(tid + 1) * NB + myb];
  }
}

extern "C" void kernel_launch(void* const* d_in, const int* in_sizes, int n_in,
                              void* d_out, int out_size, void* d_ws, size_t ws_size,
                              hipStream_t stream) {
  const int*   instr   = (const int*)d_in[0];
  const int*   trueact = (const int*)d_in[1];
  const float* isv     = (const float*)d_in[2];
  // d_in[3] = program_emb (unused by reference math)
  const float* prim    = (const float*)d_in[4];
  const float* gate_w  = (const float*)d_in[5];
  const float* gate_b  = (const float*)d_in[6];
  // d_in[7] = w_ih (multiplied by zeros; only b_ih matters)
  const float* w_hh    = (const float*)d_in[8];
  const float* b_ih    = (const float*)d_in[9];
  const float* b_hh    = (const float*)d_in[10];
  const float* out_w   = (const float*)d_in[11];
  const float* out_b   = (const float*)d_in[12];
  float* outp = (float*)d_out;

  unsigned int* ctrs = (unsigned int*)d_ws;              // 16 groups * 128B
  unsigned int* hbuf = (unsigned int*)((char*)d_ws + 4096);  // 2 * 256 * 512 u32 = 1 MB

  hipMemsetAsync(d_ws, 0, 4096, stream);

  void* args[] = { (void*)&instr, (void*)&trueact, (void*)&isv, (void*)&prim,
                   (void*)&gate_w, (void*)&gate_b, (void*)&w_hh, (void*)&b_ih,
                   (void*)&b_hh, (void*)&out_w, (void*)&out_b, (void*)&outp,
                   (void*)&ctrs, (void*)&hbuf };
  hipLaunchCooperativeKernel((const void*)sym_kernel, dim3(NWG), dim3(NTHR),
                             args, 0, stream);
}